// Round 3
// baseline (24237.175 us; speedup 1.0000x reference)
//
#include <hip/hip_runtime.h>

// 2-layer LSTM (B=128,T=512,I=512,H=1024) + linear (O=512) on gfx950.
// Persistent cooperative kernel: 256 blocks x 512 thr, 514 iterations,
// custom hierarchical grid barrier. Blocks 0-127 = layer0 (computes h1[s]
// and xg1 partial W_ih1@h1[s-1]); blocks 128-255 = layer1 two steps behind.
// R5 (this round):
//  * minimal-diff Wih1-in-LDS vs the passing R3: 128 KB dynamic LDS
//    ([0,64K) Whh slice, [64K,128K) Wih1 slice for L0 blocks); loop
//    structure/pragmas byte-identical to R3, only the s2/s3 B-frag source
//    changed from global stream to LDS. Kills the 512 KB/CU/step global
//    Wih1 stream + its LLC refetch (R1 diagnosis).
//  * provable coherence: release fence (agent) before barrier arrive,
//    acquire fence (agent, emits buffer_inv) after barrier wait. The old
//    "readers only touch fresh lines" assumption had a speculative-fill
//    hole (R4's nondeterministic failure: 3.2e-3 vs 468 absmax across
//    runs). Invalidate is ~free now: recurrent weights live in LDS, so
//    almost no cross-step L2 reuse remains to lose.

#define B_ 128
#define T_ 512
#define I_ 512
#define H_ 1024
#define O_ 512

typedef __attribute__((ext_vector_type(8))) __bf16 bf16x8;
typedef __attribute__((ext_vector_type(4))) float f32x4;

__device__ __forceinline__ float sigf(float x) { return 1.f / (1.f + __expf(-x)); }
__device__ __forceinline__ float tanh_fast(float x) { return 2.f / (1.f + __expf(-2.f * x)) - 1.f; }

// ---- coherent (LLC-level) memory ops: bypass non-coherent per-XCD L2 ----
__device__ __forceinline__ void st_bf16_coh(__bf16* p, float v) {
    unsigned short u = __builtin_bit_cast(unsigned short, (__bf16)v);
    unsigned int uu = u;
    asm volatile("global_store_short %0, %1, off sc0 sc1" :: "v"(p), "v"(uu) : "memory");
}
__device__ __forceinline__ void st_f32x4_coh(float* p, f32x4 v) {
    asm volatile("global_store_dwordx4 %0, %1, off sc0 sc1" :: "v"(p), "v"(v) : "memory");
}

// ---- hierarchical grid barrier, split arrive/wait, agent-scope fenced ----
__device__ __forceinline__ void gbar_arrive(int* cnt, int* root) {
    asm volatile("s_waitcnt vmcnt(0) lgkmcnt(0)" ::: "memory");
    __syncthreads();
    __builtin_amdgcn_fence(__ATOMIC_RELEASE, "agent");   // publish our stores
    if (threadIdx.x == 0) {
        int g = blockIdx.x & 31;
        int old = __hip_atomic_fetch_add(&cnt[g * 32], 1, __ATOMIC_RELAXED, __HIP_MEMORY_SCOPE_AGENT);
        if ((old & 7) == 7)
            __hip_atomic_fetch_add(root, 1, __ATOMIC_RELAXED, __HIP_MEMORY_SCOPE_AGENT);
    }
}
__device__ __forceinline__ void gbar_wait(int* root, int round) {
    if (threadIdx.x == 0) {
        int target = 32 * (round + 1);
        long guard = 0;
        while (__hip_atomic_load(root, __ATOMIC_RELAXED, __HIP_MEMORY_SCOPE_AGENT) < target) {
            __builtin_amdgcn_s_sleep(2);
            if (++guard > (1L << 28)) break;   // safety valve: wrong > hung
        }
    }
    __syncthreads();
    // invalidate any stale L1/L2 lines (incl. speculative fills) BEFORE the
    // consumer loads of this step; everything fresh comes from LLC.
    __builtin_amdgcn_fence(__ATOMIC_ACQUIRE, "agent");
    asm volatile("" ::: "memory");
}

// 4x4 transpose across a lane quad (lanes grouped by bits [1:0]).
__device__ __forceinline__ f32x4 quad_transpose(f32x4 v, int q) {
    f32x4 b, c2, e, d;
#pragma unroll
    for (int r = 0; r < 4; ++r) b[r] = __shfl_xor(v[r], 1);
#pragma unroll
    for (int r = 0; r < 4; ++r) c2[r] = ((q ^ r) & 1) ? b[r ^ 1] : v[r];
#pragma unroll
    for (int r = 0; r < 4; ++r) e[r] = __shfl_xor(c2[r], 2);
#pragma unroll
    for (int r = 0; r < 4; ++r) d[r] = ((q ^ r) & 2) ? e[r ^ 2] : c2[r];
    return d;
}

// phase-x: xacc = W_ih0 @ x_t for one timestep. Static inputs only -> runs
// between barrier arrive and wait. Bulk A prefetch + grouped B prefetch.
__device__ __forceinline__ void phase_x_compute(const __bf16* __restrict__ Ax,
                                                const __bf16* __restrict__ myWih0,
                                                f32x4& xa0, f32x4& xa1) {
    bf16x8 avx[16];
#pragma unroll
    for (int c = 0; c < 16; ++c) avx[c] = *(const bf16x8*)(Ax + c * 32);
    f32x4 a0 = {0, 0, 0, 0}, a1 = {0, 0, 0, 0};
#pragma unroll
    for (int g = 0; g < 4; ++g) {
        bf16x8 b0v[4], b1v[4];
#pragma unroll
        for (int u = 0; u < 4; ++u) {
            const int c = g * 4 + u;
            b0v[u] = *(const bf16x8*)(myWih0 + (c * 2 + 0) * 512);
            b1v[u] = *(const bf16x8*)(myWih0 + (c * 2 + 1) * 512);
        }
#pragma unroll
        for (int u = 0; u < 4; ++u) {
            const int c = g * 4 + u;
            a0 = __builtin_amdgcn_mfma_f32_16x16x32_bf16(avx[c], b0v[u], a0, 0, 0, 0);
            a1 = __builtin_amdgcn_mfma_f32_16x16x32_bf16(avx[c], b1v[u], a1, 0, 0, 0);
        }
    }
    xa0 = a0; xa1 = a1;
}

// ---------------- prep kernels ----------------

__global__ void pack_img_kernel(const float* __restrict__ Wsrc, __bf16* __restrict__ img,
                                int C, int Ksrc) {
    int nb = blockIdx.x, c = blockIdx.y;
    int tid = threadIdx.x;              // 256
    int ns = tid >> 7, l = (tid >> 1) & 63, j0 = (tid & 1) * 4;
    int P = nb * 32 + ns * 16 + (l & 15);
    int orow = (P & 3) * H_ + (P >> 2);
    int k = c * 32 + ((l >> 4) * 8) + j0;
    const float* src = Wsrc + (size_t)orow * Ksrc + k;
    __bf16* dst = img + ((((size_t)(nb * C + c) * 2 + ns) * 64 + l) * 8 + j0);
    dst[0] = (__bf16)src[0]; dst[1] = (__bf16)src[1];
    dst[2] = (__bf16)src[2]; dst[3] = (__bf16)src[3];
}

__global__ void pack_bias_kernel(const float* __restrict__ bi, const float* __restrict__ bh,
                                 float* __restrict__ bp) {
    int P = blockIdx.x * 256 + threadIdx.x;   // 0..4095 permuted row
    int orow = (P & 3) * H_ + (P >> 2);
    bp[P] = bi[orow] + bh[orow];
}

__global__ void pack_lin_kernel(const float* __restrict__ W, __bf16* __restrict__ Wb) {
    size_t i = (size_t)blockIdx.x * 256 + threadIdx.x;
    Wb[i] = (__bf16)W[i];
}

__global__ void xpose_kernel(const float* __restrict__ x, __bf16* __restrict__ xb) {
    int blk = blockIdx.x;              // b*T + t
    int b = blk >> 9, t = blk & (T_ - 1);
    const float* src = x + ((size_t)b * T_ + t) * I_;
    __bf16* dst = xb + ((size_t)t * B_ + b) * I_;
    int c = threadIdx.x * 2;
    float2 v = *(const float2*)(src + c);
    dst[c] = (__bf16)v.x;
    dst[c + 1] = (__bf16)v.y;
}

// ---------------- persistent LSTM kernel ----------------
// h1all/h2all: 513 slots of [128][1024] bf16; slot t+1 = h(t), slot 0 = zeros.
// xg1buf: ring of 4 slots [128][4096] f32; xg for t1 lives in slot (t1+1)&3.
// Dynamic LDS 128 KB: [0,64K) = Whh slice image, [64K,128K) = Wih1 slice (L0).

__launch_bounds__(512, 2)
__global__ void lstm_persist(
    const __bf16* __restrict__ Whh0img, const __bf16* __restrict__ Wih0s,
    const __bf16* __restrict__ Whh1img, const __bf16* __restrict__ Wih1s,
    const float* __restrict__ bias0p, const float* __restrict__ bias1p,
    const __bf16* __restrict__ xb,
    __bf16* __restrict__ h1all, __bf16* __restrict__ h2all,
    float* __restrict__ xg1buf,
    int* bar_cnt, int* bar_root)
{
    const int blk = blockIdx.x;
    const bool isL1 = blk >= 128;
    const int nb = isL1 ? blk - 128 : blk;
    const int tid = threadIdx.x;
    const int w = tid >> 6, l = tid & 63;
    const int rl = l & 15, kcol = (l >> 4) * 8;
    const int q = l & 3, aIdx = (l >> 2) & 3, rowq = l >> 4;
    const int bRow = 16 * w + rowq * 4 + q;       // after-transpose batch index

    extern __shared__ char dynLDS[];
    __bf16* WL = (__bf16*)dynLDS;                 // [32 chunks][2][64][8] Whh
    __bf16* WI = WL + 32768;                      // same layout, Wih1 (L0 only)

    // resident weight slices -> LDS (once)
    {
        const uint4* srcW = (const uint4*)((isL1 ? Whh1img : Whh0img) + (size_t)nb * 32768);
        uint4* dst = (uint4*)WL;
        for (int i = tid; i < 4096; i += 512) dst[i] = srcW[i];
        if (!isL1) {
            const uint4* srcI = (const uint4*)(Wih1s + (size_t)nb * 32768);
            for (int i = tid; i < 4096; i += 512) dst[4096 + i] = srcI[i];
        }
    }
    // bias in registers (after-transpose layout)
    float bias_r[2][4];
    {
        const float* bp = (isL1 ? bias1p : bias0p) + nb * 32;
#pragma unroll
        for (int ns = 0; ns < 2; ++ns)
#pragma unroll
            for (int g = 0; g < 4; ++g)
                bias_r[ns][g] = bp[ns * 16 + aIdx * 4 + g];
    }
    __syncthreads();

    const __bf16* myWih0 = Wih0s + (size_t)nb * 16384 + (size_t)l * 8;  // C=16 image
    const __bf16* myWL = WL + l * 8;
    const __bf16* myWI = WI + l * 8;

    float cst[2] = {0.f, 0.f};
    f32x4 xa0 = {0, 0, 0, 0}, xa1 = {0, 0, 0, 0};

    // prologue: xacc for t=0 (no dependencies)
    if (!isL1)
        phase_x_compute(xb + ((size_t)0 * B_ + 16 * w + rl) * I_ + kcol, myWih0, xa0, xa1);

    for (int s = 0; s <= 513; ++s) {
        if (!isL1) {
            if (s < T_) {
                const int t = s;
                f32x4 a0 = xa0, a1 = xa1, a2 = {0,0,0,0}, a3 = {0,0,0,0};
                // phase-h: gates0 += W_hh0 @ h1[t-1]; xg1 += W_ih1 @ h1[t-1]
                // Deep prefetch: all 32 A fragments first (one LLC latency).
                const __bf16* Ah = h1all + ((size_t)t * B_ + 16 * w + rl) * H_ + kcol; // slot t = h1[t-1]
                bf16x8 avs[32];
#pragma unroll
                for (int c = 0; c < 32; ++c) avs[c] = *(const bf16x8*)(Ah + c * 32);
#pragma unroll
                for (int g = 0; g < 8; ++g) {
                    bf16x8 s2v[4], s3v[4];
#pragma unroll
                    for (int u = 0; u < 4; ++u) {
                        const int c = g * 4 + u;
                        s2v[u] = *(const bf16x8*)(myWI + (c * 2 + 0) * 512);
                        s3v[u] = *(const bf16x8*)(myWI + (c * 2 + 1) * 512);
                    }
#pragma unroll
                    for (int u = 0; u < 4; ++u) {
                        const int c = g * 4 + u;
                        bf16x8 b0 = *(const bf16x8*)(myWL + (c * 2 + 0) * 512);
                        bf16x8 b1 = *(const bf16x8*)(myWL + (c * 2 + 1) * 512);
                        a0 = __builtin_amdgcn_mfma_f32_16x16x32_bf16(avs[c], b0, a0, 0, 0, 0);
                        a1 = __builtin_amdgcn_mfma_f32_16x16x32_bf16(avs[c], b1, a1, 0, 0, 0);
                        a2 = __builtin_amdgcn_mfma_f32_16x16x32_bf16(avs[c], s2v[u], a2, 0, 0, 0);
                        a3 = __builtin_amdgcn_mfma_f32_16x16x32_bf16(avs[c], s3v[u], a3, 0, 0, 0);
                    }
                }
                // epilogue: LSTM0 update (wave-local, c in registers)
                f32x4 accs[2] = {a0, a1};
#pragma unroll
                for (int ns = 0; ns < 2; ++ns) {
                    f32x4 g4 = quad_transpose(accs[ns], q);
                    float iv = sigf(g4[0] + bias_r[ns][0]);
                    float fv = sigf(g4[1] + bias_r[ns][1]);
                    float gv = tanh_fast(g4[2] + bias_r[ns][2]);
                    float ov = sigf(g4[3] + bias_r[ns][3]);
                    float cn = fv * cst[ns] + iv * gv;
                    cst[ns] = cn;
                    float hv = ov * tanh_fast(cn);
                    __bf16* hp = h1all + ((size_t)(t + 1) * B_ + bRow) * H_ + (nb * 8 + ns * 4 + aIdx);
                    st_bf16_coh(hp, hv);
                }
                // xg1 partial store: W_ih1 @ h1[t-1] = xg for t1=t-1, slot t&3
                f32x4 accx[2] = {a2, a3};
#pragma unroll
                for (int ns = 0; ns < 2; ++ns) {
                    f32x4 x4 = quad_transpose(accx[ns], q);
                    float* p = xg1buf + ((size_t)(t & 3) * B_ + bRow) * 4096
                             + nb * 32 + ns * 16 + aIdx * 4;
                    st_f32x4_coh(p, x4);
                }
            } else if (s == T_) {
                // xg-only tail: W_ih1 @ h1[511] -> slot 0, consumed at s=513.
                f32x4 a2 = {0,0,0,0}, a3 = {0,0,0,0};
                const __bf16* Ah = h1all + ((size_t)T_ * B_ + 16 * w + rl) * H_ + kcol;
                bf16x8 avs[32];
#pragma unroll
                for (int c = 0; c < 32; ++c) avs[c] = *(const bf16x8*)(Ah + c * 32);
#pragma unroll
                for (int g = 0; g < 8; ++g) {
                    bf16x8 s2v[4], s3v[4];
#pragma unroll
                    for (int u = 0; u < 4; ++u) {
                        const int c = g * 4 + u;
                        s2v[u] = *(const bf16x8*)(myWI + (c * 2 + 0) * 512);
                        s3v[u] = *(const bf16x8*)(myWI + (c * 2 + 1) * 512);
                    }
#pragma unroll
                    for (int u = 0; u < 4; ++u) {
                        const int c = g * 4 + u;
                        a2 = __builtin_amdgcn_mfma_f32_16x16x32_bf16(avs[c], s2v[u], a2, 0, 0, 0);
                        a3 = __builtin_amdgcn_mfma_f32_16x16x32_bf16(avs[c], s3v[u], a3, 0, 0, 0);
                    }
                }
                f32x4 accx[2] = {a2, a3};
#pragma unroll
                for (int ns = 0; ns < 2; ++ns) {
                    f32x4 x4 = quad_transpose(accx[ns], q);
                    float* p = xg1buf + ((size_t)(T_ & 3) * B_ + bRow) * 4096
                             + nb * 32 + ns * 16 + aIdx * 4;
                    st_f32x4_coh(p, x4);
                }
            }
        } else {
            if (s >= 2) {
                const int t1 = s - 2;
                // issue xg loads early (LLC latency hides under MFMA loop)
                const float* p0 = xg1buf + ((size_t)((t1 + 1) & 3) * B_ + bRow) * 4096 + nb * 32 + aIdx * 4;
                const float* p1 = p0 + 16;
                f32x4 x0, x1;
                asm volatile("global_load_dwordx4 %0, %2, off sc0 sc1\n\t"
                             "global_load_dwordx4 %1, %3, off sc0 sc1"
                             : "=&v"(x0), "=&v"(x1) : "v"(p0), "v"(p1) : "memory");
                const __bf16* Ah = h2all + ((size_t)t1 * B_ + 16 * w + rl) * H_ + kcol; // slot t1 = h2[t1-1]
                bf16x8 avs[32];
#pragma unroll
                for (int c = 0; c < 32; ++c) avs[c] = *(const bf16x8*)(Ah + c * 32);
                f32x4 a0 = {0,0,0,0}, a1 = {0,0,0,0};
#pragma unroll
                for (int c = 0; c < 32; ++c) {
                    bf16x8 b0 = *(const bf16x8*)(myWL + (c * 2 + 0) * 512);
                    bf16x8 b1 = *(const bf16x8*)(myWL + (c * 2 + 1) * 512);
                    a0 = __builtin_amdgcn_mfma_f32_16x16x32_bf16(avs[c], b0, a0, 0, 0, 0);
                    a1 = __builtin_amdgcn_mfma_f32_16x16x32_bf16(avs[c], b1, a1, 0, 0, 0);
                }
                // join the early xg loads (all prefetches are consumed by now)
                asm volatile("s_waitcnt vmcnt(0)" : "+v"(x0), "+v"(x1) :: "memory");
                f32x4 accs[2] = {a0, a1};
                f32x4 xgs[2] = {x0, x1};
#pragma unroll
                for (int ns = 0; ns < 2; ++ns) {
                    f32x4 g4 = quad_transpose(accs[ns], q);
                    float iv = sigf(g4[0] + xgs[ns][0] + bias_r[ns][0]);
                    float fv = sigf(g4[1] + xgs[ns][1] + bias_r[ns][1]);
                    float gv = tanh_fast(g4[2] + xgs[ns][2] + bias_r[ns][2]);
                    float ov = sigf(g4[3] + xgs[ns][3] + bias_r[ns][3]);
                    float cn = fv * cst[ns] + iv * gv;
                    cst[ns] = cn;
                    float hv = ov * tanh_fast(cn);
                    __bf16* hp = h2all + ((size_t)(t1 + 1) * B_ + bRow) * H_ + (nb * 8 + ns * 4 + aIdx);
                    st_bf16_coh(hp, hv);
                }
            }
        }
        if (s < 513) {
            gbar_arrive(bar_cnt, bar_root);
            // overlap: next step's input GEMM (static data) hides barrier latency
            if (!isL1 && (s + 1) < T_)
                phase_x_compute(xb + ((size_t)(s + 1) * B_ + 16 * w + rl) * I_ + kcol,
                                myWih0, xa0, xa1);
            gbar_wait(bar_root, s);
        }
    }
}

// ---------------- final linear ----------------

__launch_bounds__(256, 2)
__global__ void final_kernel(const __bf16* __restrict__ h2base,
                             const __bf16* __restrict__ Wlin,
                             const float* __restrict__ blin,
                             float* __restrict__ out)
{
    const int mb = blockIdx.x >> 4;
    const int nb = blockIdx.x & 15;
    const int tid = threadIdx.x, w = tid >> 6, l = tid & 63;
    __shared__ __bf16 As[128][32];
    __shared__ __bf16 Bs[32][32];
    f32x4 acc00 = {0,0,0,0}, acc01 = {0,0,0,0}, acc10 = {0,0,0,0}, acc11 = {0,0,0,0};
    const int arow = tid >> 1, acol = (tid & 1) * 16;
    const int brow = tid >> 3, bcol = (tid & 7) * 4;
    const __bf16* abase = h2base + ((size_t)mb * 128 + arow) * H_ + acol;
    const __bf16* wrow = Wlin + (size_t)(nb * 32 + brow) * H_ + bcol;
    for (int kb = 0; kb < H_ / 32; ++kb) {
        const int k0 = kb * 32;
        __syncthreads();
        *(bf16x8*)&As[arow][acol]     = *(const bf16x8*)(abase + k0);
        *(bf16x8*)&As[arow][acol + 8] = *(const bf16x8*)(abase + k0 + 8);
        *(uint2*)&Bs[brow][bcol]      = *(const uint2*)(wrow + k0);
        __syncthreads();
        bf16x8 a0 = *(const bf16x8*)&As[w * 32 + (l & 15)][(l >> 4) * 8];
        bf16x8 a1 = *(const bf16x8*)&As[w * 32 + 16 + (l & 15)][(l >> 4) * 8];
        bf16x8 b0 = *(const bf16x8*)&Bs[(l & 15)][(l >> 4) * 8];
        bf16x8 b1 = *(const bf16x8*)&Bs[16 + (l & 15)][(l >> 4) * 8];
        acc00 = __builtin_amdgcn_mfma_f32_16x16x32_bf16(a0, b0, acc00, 0, 0, 0);
        acc01 = __builtin_amdgcn_mfma_f32_16x16x32_bf16(a0, b1, acc01, 0, 0, 0);
        acc10 = __builtin_amdgcn_mfma_f32_16x16x32_bf16(a1, b0, acc10, 0, 0, 0);
        acc11 = __builtin_amdgcn_mfma_f32_16x16x32_bf16(a1, b1, acc11, 0, 0, 0);
    }
    const int r0 = (l >> 4) * 4, cA = l & 15;
#pragma unroll
    for (int mi = 0; mi < 2; ++mi)
#pragma unroll
        for (int ni = 0; ni < 2; ++ni) {
            f32x4 acc = (mi == 0) ? (ni == 0 ? acc00 : acc01) : (ni == 0 ? acc10 : acc11);
#pragma unroll
            for (int r = 0; r < 4; ++r) {
                int a = mb * 128 + w * 32 + mi * 16 + r0 + r;
                int o = nb * 32 + ni * 16 + cA;
                int b = a & 127, t = a >> 7;
                out[(size_t)b * (T_ * O_) + (size_t)t * O_ + o] = acc[r] + blin[o];
            }
        }
}

// ---------------- launch ----------------

extern "C" void kernel_launch(void* const* d_in, const int* in_sizes, int n_in,
                              void* d_out, int out_size, void* d_ws, size_t ws_size,
                              hipStream_t stream) {
    const float* x     = (const float*)d_in[0];
    const float* W_ih0 = (const float*)d_in[1];
    const float* W_hh0 = (const float*)d_in[2];
    const float* b_ih0 = (const float*)d_in[3];
    const float* b_hh0 = (const float*)d_in[4];
    const float* W_ih1 = (const float*)d_in[5];
    const float* W_hh1 = (const float*)d_in[6];
    const float* b_ih1 = (const float*)d_in[7];
    const float* b_hh1 = (const float*)d_in[8];
    const float* W_lin = (const float*)d_in[9];
    const float* b_lin = (const float*)d_in[10];
    float* out = (float*)d_out;

    char* ws = (char*)d_ws;
    __bf16* Whh0img = (__bf16*)ws; ws += (size_t)4096 * 1024 * 2;      // 8.4 MB
    __bf16* Wih0s   = (__bf16*)ws; ws += (size_t)4096 * 512 * 2;       // 4.2 MB
    __bf16* Whh1img = (__bf16*)ws; ws += (size_t)4096 * 1024 * 2;      // 8.4 MB
    __bf16* Wih1s   = (__bf16*)ws; ws += (size_t)4096 * 1024 * 2;      // 8.4 MB
    __bf16* Wlb     = (__bf16*)ws; ws += (size_t)512 * 1024 * 2;       // 1 MB
    float* bias0p   = (float*)ws;  ws += (size_t)4096 * 4;
    float* bias1p   = (float*)ws;  ws += (size_t)4096 * 4;
    __bf16* xb      = (__bf16*)ws; ws += (size_t)T_ * B_ * I_ * 2;     // 67 MB
    __bf16* h1all   = (__bf16*)ws; ws += (size_t)(T_ + 1) * B_ * H_ * 2; // 134.5 MB
    __bf16* h2all   = (__bf16*)ws; ws += (size_t)(T_ + 1) * B_ * H_ * 2; // 134.5 MB
    float* xg1buf   = (float*)ws;  ws += (size_t)4 * B_ * 4096 * 4;    // 8.4 MB
    int* bar_cnt    = (int*)ws;    ws += 4096;                          // 32 groups, 128B apart
    int* bar_root   = (int*)ws;    ws += 4096;

    // prep
    pack_img_kernel<<<dim3(128, 32), 256, 0, stream>>>(W_hh0, Whh0img, 32, H_);
    pack_img_kernel<<<dim3(128, 16), 256, 0, stream>>>(W_ih0, Wih0s, 16, I_);
    pack_img_kernel<<<dim3(128, 32), 256, 0, stream>>>(W_hh1, Whh1img, 32, H_);
    pack_img_kernel<<<dim3(128, 32), 256, 0, stream>>>(W_ih1, Wih1s, 32, H_);
    pack_bias_kernel<<<16, 256, 0, stream>>>(b_ih0, b_hh0, bias0p);
    pack_bias_kernel<<<16, 256, 0, stream>>>(b_ih1, b_hh1, bias1p);
    pack_lin_kernel<<<(512 * 1024) / 256, 256, 0, stream>>>(W_lin, Wlb);
    xpose_kernel<<<B_ * T_, 256, 0, stream>>>(x, xb);
    hipMemsetAsync(h1all, 0, (size_t)B_ * H_ * 2, stream);   // slot 0 = h1[-1] = 0
    hipMemsetAsync(h2all, 0, (size_t)B_ * H_ * 2, stream);   // slot 0 = h2[-1] = 0
    hipMemsetAsync(bar_cnt, 0, 8192, stream);                 // counters + root

    // persistent recurrence (cooperative: guarantees co-residency for barrier)
    {
        // allow 128 KB dynamic LDS (gfx950 has 160 KB/CU; 1 block/CU here)
        hipFuncSetAttribute((const void*)lstm_persist,
                            hipFuncAttributeMaxDynamicSharedMemorySize, 131072);
        void* kargs[] = {
            (void*)&Whh0img, (void*)&Wih0s, (void*)&Whh1img, (void*)&Wih1s,
            (void*)&bias0p, (void*)&bias1p, (void*)&xb,
            (void*)&h1all, (void*)&h2all, (void*)&xg1buf,
            (void*)&bar_cnt, (void*)&bar_root
        };
        hipLaunchCooperativeKernel((const void*)lstm_persist, dim3(256), dim3(512),
                                   kargs, 131072, stream);
    }

    // final linear: reads h2 slots 1..512
    final_kernel<<<512 * 16, 256, 0, stream>>>(h2all + (size_t)B_ * H_, Wlb, b_lin, out);
}

// Round 4
// 9236.897 us; speedup vs baseline: 2.6240x; 2.6240x over previous
//
#include <hip/hip_runtime.h>

// 2-layer LSTM (B=128,T=512,I=512,H=1024) + linear (O=512) on gfx950.
// Persistent cooperative kernel: 256 blocks x 512 thr, 514 iterations,
// custom hierarchical grid barrier. Blocks 0-127 = layer0 (computes h1[s]
// and xg1 partial W_ih1@h1[s-1]); blocks 128-255 = layer1 two steps behind.
// R6 (this round):
//  * keep Wih1-in-LDS (128 KB dynamic LDS; proven correct in R5, kills the
//    512 KB/CU/step Wih1 global stream: FETCH 7.7e6 -> 1.85e6 KB).
//  * REMOVE the agent fences (R5: whole-L2 writeback+invalidate per block
//    per step = +23 us/step — the entire regression).
//  * surgical coherence instead: the only plain-loaded cross-step data were
//    the h1all/h2all A-tiles. Those loads are now sc0 sc1 (bypass L1/L2,
//    read LLC directly) — same proven mechanism as the xg1buf ring loads.
//    No stale-copy hazard remains anywhere: every cross-step read and write
//    is LLC-coherent; static data (xb, Wih0s, weights) is read-only.
//  * A-tile loads issued as 2x16 monolithic asm blocks (all 32 fragments in
//    flight, one LLC latency), vmcnt(0) + sched_barrier(0) before MFMAs.

#define B_ 128
#define T_ 512
#define I_ 512
#define H_ 1024
#define O_ 512

typedef __attribute__((ext_vector_type(8))) __bf16 bf16x8;
typedef __attribute__((ext_vector_type(4))) float f32x4;

__device__ __forceinline__ float sigf(float x) { return 1.f / (1.f + __expf(-x)); }
__device__ __forceinline__ float tanh_fast(float x) { return 2.f / (1.f + __expf(-2.f * x)) - 1.f; }

// ---- coherent (LLC-level) memory ops: bypass non-coherent per-XCD L1/L2 ----
__device__ __forceinline__ void st_bf16_coh(__bf16* p, float v) {
    unsigned short u = __builtin_bit_cast(unsigned short, (__bf16)v);
    unsigned int uu = u;
    asm volatile("global_store_short %0, %1, off sc0 sc1" :: "v"(p), "v"(uu) : "memory");
}
__device__ __forceinline__ void st_f32x4_coh(float* p, f32x4 v) {
    asm volatile("global_store_dwordx4 %0, %1, off sc0 sc1" :: "v"(p), "v"(v) : "memory");
}

// 16 coherent 16B loads from base + {0..15}*64B, all in flight (no waitcnt).
__device__ __forceinline__ void load16_coh(f32x4* d, const __bf16* base) {
    asm volatile(
        "global_load_dwordx4 %0, %16, off sc0 sc1\n\t"
        "global_load_dwordx4 %1, %16, off offset:64 sc0 sc1\n\t"
        "global_load_dwordx4 %2, %16, off offset:128 sc0 sc1\n\t"
        "global_load_dwordx4 %3, %16, off offset:192 sc0 sc1\n\t"
        "global_load_dwordx4 %4, %16, off offset:256 sc0 sc1\n\t"
        "global_load_dwordx4 %5, %16, off offset:320 sc0 sc1\n\t"
        "global_load_dwordx4 %6, %16, off offset:384 sc0 sc1\n\t"
        "global_load_dwordx4 %7, %16, off offset:448 sc0 sc1\n\t"
        "global_load_dwordx4 %8, %16, off offset:512 sc0 sc1\n\t"
        "global_load_dwordx4 %9, %16, off offset:576 sc0 sc1\n\t"
        "global_load_dwordx4 %10, %16, off offset:640 sc0 sc1\n\t"
        "global_load_dwordx4 %11, %16, off offset:704 sc0 sc1\n\t"
        "global_load_dwordx4 %12, %16, off offset:768 sc0 sc1\n\t"
        "global_load_dwordx4 %13, %16, off offset:832 sc0 sc1\n\t"
        "global_load_dwordx4 %14, %16, off offset:896 sc0 sc1\n\t"
        "global_load_dwordx4 %15, %16, off offset:960 sc0 sc1"
        : "=&v"(d[0]), "=&v"(d[1]), "=&v"(d[2]), "=&v"(d[3]),
          "=&v"(d[4]), "=&v"(d[5]), "=&v"(d[6]), "=&v"(d[7]),
          "=&v"(d[8]), "=&v"(d[9]), "=&v"(d[10]), "=&v"(d[11]),
          "=&v"(d[12]), "=&v"(d[13]), "=&v"(d[14]), "=&v"(d[15])
        : "v"(base) : "memory");
}
// join all outstanding vmem; sched_barrier pins consumers after it (rule #18)
__device__ __forceinline__ void vm_join() {
    asm volatile("s_waitcnt vmcnt(0)" ::: "memory");
    __builtin_amdgcn_sched_barrier(0);
}

// ---- hierarchical grid barrier, split arrive/wait (R3 version, no fences) ----
__device__ __forceinline__ void gbar_arrive(int* cnt, int* root) {
    asm volatile("s_waitcnt vmcnt(0) lgkmcnt(0)" ::: "memory");
    __syncthreads();
    if (threadIdx.x == 0) {
        int g = blockIdx.x & 31;
        int old = __hip_atomic_fetch_add(&cnt[g * 32], 1, __ATOMIC_RELAXED, __HIP_MEMORY_SCOPE_AGENT);
        if ((old & 7) == 7)
            __hip_atomic_fetch_add(root, 1, __ATOMIC_RELAXED, __HIP_MEMORY_SCOPE_AGENT);
    }
}
__device__ __forceinline__ void gbar_wait(int* root, int round) {
    if (threadIdx.x == 0) {
        int target = 32 * (round + 1);
        long guard = 0;
        while (__hip_atomic_load(root, __ATOMIC_RELAXED, __HIP_MEMORY_SCOPE_AGENT) < target) {
            __builtin_amdgcn_s_sleep(2);
            if (++guard > (1L << 28)) break;   // safety valve: wrong > hung
        }
    }
    __syncthreads();
    asm volatile("" ::: "memory");
}

// 4x4 transpose across a lane quad (lanes grouped by bits [1:0]).
__device__ __forceinline__ f32x4 quad_transpose(f32x4 v, int q) {
    f32x4 b, c2, e, d;
#pragma unroll
    for (int r = 0; r < 4; ++r) b[r] = __shfl_xor(v[r], 1);
#pragma unroll
    for (int r = 0; r < 4; ++r) c2[r] = ((q ^ r) & 1) ? b[r ^ 1] : v[r];
#pragma unroll
    for (int r = 0; r < 4; ++r) e[r] = __shfl_xor(c2[r], 2);
#pragma unroll
    for (int r = 0; r < 4; ++r) d[r] = ((q ^ r) & 2) ? e[r ^ 2] : c2[r];
    return d;
}

// phase-x: xacc = W_ih0 @ x_t for one timestep. Static read-only inputs ->
// plain warm-L2 loads, runs between barrier arrive and wait.
__device__ __forceinline__ void phase_x_compute(const __bf16* __restrict__ Ax,
                                                const __bf16* __restrict__ myWih0,
                                                f32x4& xa0, f32x4& xa1) {
    bf16x8 avx[16];
#pragma unroll
    for (int c = 0; c < 16; ++c) avx[c] = *(const bf16x8*)(Ax + c * 32);
    f32x4 a0 = {0, 0, 0, 0}, a1 = {0, 0, 0, 0};
#pragma unroll
    for (int g = 0; g < 4; ++g) {
        bf16x8 b0v[4], b1v[4];
#pragma unroll
        for (int u = 0; u < 4; ++u) {
            const int c = g * 4 + u;
            b0v[u] = *(const bf16x8*)(myWih0 + (c * 2 + 0) * 512);
            b1v[u] = *(const bf16x8*)(myWih0 + (c * 2 + 1) * 512);
        }
#pragma unroll
        for (int u = 0; u < 4; ++u) {
            const int c = g * 4 + u;
            a0 = __builtin_amdgcn_mfma_f32_16x16x32_bf16(avx[c], b0v[u], a0, 0, 0, 0);
            a1 = __builtin_amdgcn_mfma_f32_16x16x32_bf16(avx[c], b1v[u], a1, 0, 0, 0);
        }
    }
    xa0 = a0; xa1 = a1;
}

// ---------------- prep kernels ----------------

__global__ void pack_img_kernel(const float* __restrict__ Wsrc, __bf16* __restrict__ img,
                                int C, int Ksrc) {
    int nb = blockIdx.x, c = blockIdx.y;
    int tid = threadIdx.x;              // 256
    int ns = tid >> 7, l = (tid >> 1) & 63, j0 = (tid & 1) * 4;
    int P = nb * 32 + ns * 16 + (l & 15);
    int orow = (P & 3) * H_ + (P >> 2);
    int k = c * 32 + ((l >> 4) * 8) + j0;
    const float* src = Wsrc + (size_t)orow * Ksrc + k;
    __bf16* dst = img + ((((size_t)(nb * C + c) * 2 + ns) * 64 + l) * 8 + j0);
    dst[0] = (__bf16)src[0]; dst[1] = (__bf16)src[1];
    dst[2] = (__bf16)src[2]; dst[3] = (__bf16)src[3];
}

__global__ void pack_bias_kernel(const float* __restrict__ bi, const float* __restrict__ bh,
                                 float* __restrict__ bp) {
    int P = blockIdx.x * 256 + threadIdx.x;   // 0..4095 permuted row
    int orow = (P & 3) * H_ + (P >> 2);
    bp[P] = bi[orow] + bh[orow];
}

__global__ void pack_lin_kernel(const float* __restrict__ W, __bf16* __restrict__ Wb) {
    size_t i = (size_t)blockIdx.x * 256 + threadIdx.x;
    Wb[i] = (__bf16)W[i];
}

__global__ void xpose_kernel(const float* __restrict__ x, __bf16* __restrict__ xb) {
    int blk = blockIdx.x;              // b*T + t
    int b = blk >> 9, t = blk & (T_ - 1);
    const float* src = x + ((size_t)b * T_ + t) * I_;
    __bf16* dst = xb + ((size_t)t * B_ + b) * I_;
    int c = threadIdx.x * 2;
    float2 v = *(const float2*)(src + c);
    dst[c] = (__bf16)v.x;
    dst[c + 1] = (__bf16)v.y;
}

// ---------------- persistent LSTM kernel ----------------
// h1all/h2all: 513 slots of [128][1024] bf16; slot t+1 = h(t), slot 0 = zeros.
// xg1buf: ring of 4 slots [128][4096] f32; xg for t1 lives in slot (t1+1)&3.
// Dynamic LDS 128 KB: [0,64K) = Whh slice image, [64K,128K) = Wih1 slice (L0).

__launch_bounds__(512, 2)
__global__ void lstm_persist(
    const __bf16* __restrict__ Whh0img, const __bf16* __restrict__ Wih0s,
    const __bf16* __restrict__ Whh1img, const __bf16* __restrict__ Wih1s,
    const float* __restrict__ bias0p, const float* __restrict__ bias1p,
    const __bf16* __restrict__ xb,
    __bf16* __restrict__ h1all, __bf16* __restrict__ h2all,
    float* __restrict__ xg1buf,
    int* bar_cnt, int* bar_root)
{
    const int blk = blockIdx.x;
    const bool isL1 = blk >= 128;
    const int nb = isL1 ? blk - 128 : blk;
    const int tid = threadIdx.x;
    const int w = tid >> 6, l = tid & 63;
    const int rl = l & 15, kcol = (l >> 4) * 8;
    const int q = l & 3, aIdx = (l >> 2) & 3, rowq = l >> 4;
    const int bRow = 16 * w + rowq * 4 + q;       // after-transpose batch index

    extern __shared__ char dynLDS[];
    __bf16* WL = (__bf16*)dynLDS;                 // [32 chunks][2][64][8] Whh
    __bf16* WI = WL + 32768;                      // same layout, Wih1 (L0 only)

    // resident weight slices -> LDS (once)
    {
        const uint4* srcW = (const uint4*)((isL1 ? Whh1img : Whh0img) + (size_t)nb * 32768);
        uint4* dst = (uint4*)WL;
        for (int i = tid; i < 4096; i += 512) dst[i] = srcW[i];
        if (!isL1) {
            const uint4* srcI = (const uint4*)(Wih1s + (size_t)nb * 32768);
            for (int i = tid; i < 4096; i += 512) dst[4096 + i] = srcI[i];
        }
    }
    // bias in registers (after-transpose layout)
    float bias_r[2][4];
    {
        const float* bp = (isL1 ? bias1p : bias0p) + nb * 32;
#pragma unroll
        for (int ns = 0; ns < 2; ++ns)
#pragma unroll
            for (int g = 0; g < 4; ++g)
                bias_r[ns][g] = bp[ns * 16 + aIdx * 4 + g];
    }
    __syncthreads();

    const __bf16* myWih0 = Wih0s + (size_t)nb * 16384 + (size_t)l * 8;  // C=16 image
    const __bf16* myWL = WL + l * 8;
    const __bf16* myWI = WI + l * 8;

    float cst[2] = {0.f, 0.f};
    f32x4 xa0 = {0, 0, 0, 0}, xa1 = {0, 0, 0, 0};

    // prologue: xacc for t=0 (no dependencies)
    if (!isL1)
        phase_x_compute(xb + ((size_t)0 * B_ + 16 * w + rl) * I_ + kcol, myWih0, xa0, xa1);

    for (int s = 0; s <= 513; ++s) {
        if (!isL1) {
            if (s < T_) {
                const int t = s;
                f32x4 a0 = xa0, a1 = xa1, a2 = {0,0,0,0}, a3 = {0,0,0,0};
                // phase-h: gates0 += W_hh0 @ h1[t-1]; xg1 += W_ih1 @ h1[t-1]
                // A-tile: 32 coherent (LLC) loads, all in flight, one join.
                const __bf16* Ah = h1all + ((size_t)t * B_ + 16 * w + rl) * H_ + kcol; // slot t = h1[t-1]
                f32x4 raw[32];
                load16_coh(raw, Ah);
                load16_coh(raw + 16, Ah + 512);
                vm_join();
#pragma unroll
                for (int c = 0; c < 32; ++c) {
                    bf16x8 av = __builtin_bit_cast(bf16x8, raw[c]);
                    bf16x8 b0 = *(const bf16x8*)(myWL + (c * 2 + 0) * 512);
                    bf16x8 b1 = *(const bf16x8*)(myWL + (c * 2 + 1) * 512);
                    bf16x8 s2 = *(const bf16x8*)(myWI + (c * 2 + 0) * 512);
                    bf16x8 s3 = *(const bf16x8*)(myWI + (c * 2 + 1) * 512);
                    a0 = __builtin_amdgcn_mfma_f32_16x16x32_bf16(av, b0, a0, 0, 0, 0);
                    a1 = __builtin_amdgcn_mfma_f32_16x16x32_bf16(av, b1, a1, 0, 0, 0);
                    a2 = __builtin_amdgcn_mfma_f32_16x16x32_bf16(av, s2, a2, 0, 0, 0);
                    a3 = __builtin_amdgcn_mfma_f32_16x16x32_bf16(av, s3, a3, 0, 0, 0);
                }
                // epilogue: LSTM0 update (wave-local, c in registers)
                f32x4 accs[2] = {a0, a1};
#pragma unroll
                for (int ns = 0; ns < 2; ++ns) {
                    f32x4 g4 = quad_transpose(accs[ns], q);
                    float iv = sigf(g4[0] + bias_r[ns][0]);
                    float fv = sigf(g4[1] + bias_r[ns][1]);
                    float gv = tanh_fast(g4[2] + bias_r[ns][2]);
                    float ov = sigf(g4[3] + bias_r[ns][3]);
                    float cn = fv * cst[ns] + iv * gv;
                    cst[ns] = cn;
                    float hv = ov * tanh_fast(cn);
                    __bf16* hp = h1all + ((size_t)(t + 1) * B_ + bRow) * H_ + (nb * 8 + ns * 4 + aIdx);
                    st_bf16_coh(hp, hv);
                }
                // xg1 partial store: W_ih1 @ h1[t-1] = xg for t1=t-1, slot t&3
                f32x4 accx[2] = {a2, a3};
#pragma unroll
                for (int ns = 0; ns < 2; ++ns) {
                    f32x4 x4 = quad_transpose(accx[ns], q);
                    float* p = xg1buf + ((size_t)(t & 3) * B_ + bRow) * 4096
                             + nb * 32 + ns * 16 + aIdx * 4;
                    st_f32x4_coh(p, x4);
                }
            } else if (s == T_) {
                // xg-only tail: W_ih1 @ h1[511] -> slot 0, consumed at s=513.
                f32x4 a2 = {0,0,0,0}, a3 = {0,0,0,0};
                const __bf16* Ah = h1all + ((size_t)T_ * B_ + 16 * w + rl) * H_ + kcol;
                f32x4 raw[32];
                load16_coh(raw, Ah);
                load16_coh(raw + 16, Ah + 512);
                vm_join();
#pragma unroll
                for (int c = 0; c < 32; ++c) {
                    bf16x8 av = __builtin_bit_cast(bf16x8, raw[c]);
                    bf16x8 s2 = *(const bf16x8*)(myWI + (c * 2 + 0) * 512);
                    bf16x8 s3 = *(const bf16x8*)(myWI + (c * 2 + 1) * 512);
                    a2 = __builtin_amdgcn_mfma_f32_16x16x32_bf16(av, s2, a2, 0, 0, 0);
                    a3 = __builtin_amdgcn_mfma_f32_16x16x32_bf16(av, s3, a3, 0, 0, 0);
                }
                f32x4 accx[2] = {a2, a3};
#pragma unroll
                for (int ns = 0; ns < 2; ++ns) {
                    f32x4 x4 = quad_transpose(accx[ns], q);
                    float* p = xg1buf + ((size_t)(T_ & 3) * B_ + bRow) * 4096
                             + nb * 32 + ns * 16 + aIdx * 4;
                    st_f32x4_coh(p, x4);
                }
            }
        } else {
            if (s >= 2) {
                const int t1 = s - 2;
                // issue xg loads early (coherent; LLC latency hides under A loads)
                const float* p0 = xg1buf + ((size_t)((t1 + 1) & 3) * B_ + bRow) * 4096 + nb * 32 + aIdx * 4;
                const float* p1 = p0 + 16;
                f32x4 x0, x1;
                asm volatile("global_load_dwordx4 %0, %2, off sc0 sc1\n\t"
                             "global_load_dwordx4 %1, %3, off sc0 sc1"
                             : "=&v"(x0), "=&v"(x1) : "v"(p0), "v"(p1) : "memory");
                const __bf16* Ah = h2all + ((size_t)t1 * B_ + 16 * w + rl) * H_ + kcol; // slot t1 = h2[t1-1]
                f32x4 raw[32];
                load16_coh(raw, Ah);
                load16_coh(raw + 16, Ah + 512);
                vm_join();   // joins A-tile AND the xg loads
                f32x4 a0 = {0,0,0,0}, a1 = {0,0,0,0};
#pragma unroll
                for (int c = 0; c < 32; ++c) {
                    bf16x8 av = __builtin_bit_cast(bf16x8, raw[c]);
                    bf16x8 b0 = *(const bf16x8*)(myWL + (c * 2 + 0) * 512);
                    bf16x8 b1 = *(const bf16x8*)(myWL + (c * 2 + 1) * 512);
                    a0 = __builtin_amdgcn_mfma_f32_16x16x32_bf16(av, b0, a0, 0, 0, 0);
                    a1 = __builtin_amdgcn_mfma_f32_16x16x32_bf16(av, b1, a1, 0, 0, 0);
                }
                f32x4 accs[2] = {a0, a1};
                f32x4 xgs[2] = {x0, x1};
#pragma unroll
                for (int ns = 0; ns < 2; ++ns) {
                    f32x4 g4 = quad_transpose(accs[ns], q);
                    float iv = sigf(g4[0] + xgs[ns][0] + bias_r[ns][0]);
                    float fv = sigf(g4[1] + xgs[ns][1] + bias_r[ns][1]);
                    float gv = tanh_fast(g4[2] + xgs[ns][2] + bias_r[ns][2]);
                    float ov = sigf(g4[3] + xgs[ns][3] + bias_r[ns][3]);
                    float cn = fv * cst[ns] + iv * gv;
                    cst[ns] = cn;
                    float hv = ov * tanh_fast(cn);
                    __bf16* hp = h2all + ((size_t)(t1 + 1) * B_ + bRow) * H_ + (nb * 8 + ns * 4 + aIdx);
                    st_bf16_coh(hp, hv);
                }
            }
        }
        if (s < 513) {
            gbar_arrive(bar_cnt, bar_root);
            // overlap: next step's input GEMM (static data) hides barrier latency
            if (!isL1 && (s + 1) < T_)
                phase_x_compute(xb + ((size_t)(s + 1) * B_ + 16 * w + rl) * I_ + kcol,
                                myWih0, xa0, xa1);
            gbar_wait(bar_root, s);
        }
    }
}

// ---------------- final linear ----------------

__launch_bounds__(256, 2)
__global__ void final_kernel(const __bf16* __restrict__ h2base,
                             const __bf16* __restrict__ Wlin,
                             const float* __restrict__ blin,
                             float* __restrict__ out)
{
    const int mb = blockIdx.x >> 4;
    const int nb = blockIdx.x & 15;
    const int tid = threadIdx.x, w = tid >> 6, l = tid & 63;
    __shared__ __bf16 As[128][32];
    __shared__ __bf16 Bs[32][32];
    f32x4 acc00 = {0,0,0,0}, acc01 = {0,0,0,0}, acc10 = {0,0,0,0}, acc11 = {0,0,0,0};
    const int arow = tid >> 1, acol = (tid & 1) * 16;
    const int brow = tid >> 3, bcol = (tid & 7) * 4;
    const __bf16* abase = h2base + ((size_t)mb * 128 + arow) * H_ + acol;
    const __bf16* wrow = Wlin + (size_t)(nb * 32 + brow) * H_ + bcol;
    for (int kb = 0; kb < H_ / 32; ++kb) {
        const int k0 = kb * 32;
        __syncthreads();
        *(bf16x8*)&As[arow][acol]     = *(const bf16x8*)(abase + k0);
        *(bf16x8*)&As[arow][acol + 8] = *(const bf16x8*)(abase + k0 + 8);
        *(uint2*)&Bs[brow][bcol]      = *(const uint2*)(wrow + k0);
        __syncthreads();
        bf16x8 a0 = *(const bf16x8*)&As[w * 32 + (l & 15)][(l >> 4) * 8];
        bf16x8 a1 = *(const bf16x8*)&As[w * 32 + 16 + (l & 15)][(l >> 4) * 8];
        bf16x8 b0 = *(const bf16x8*)&Bs[(l & 15)][(l >> 4) * 8];
        bf16x8 b1 = *(const bf16x8*)&Bs[16 + (l & 15)][(l >> 4) * 8];
        acc00 = __builtin_amdgcn_mfma_f32_16x16x32_bf16(a0, b0, acc00, 0, 0, 0);
        acc01 = __builtin_amdgcn_mfma_f32_16x16x32_bf16(a0, b1, acc01, 0, 0, 0);
        acc10 = __builtin_amdgcn_mfma_f32_16x16x32_bf16(a1, b0, acc10, 0, 0, 0);
        acc11 = __builtin_amdgcn_mfma_f32_16x16x32_bf16(a1, b1, acc11, 0, 0, 0);
    }
    const int r0 = (l >> 4) * 4, cA = l & 15;
#pragma unroll
    for (int mi = 0; mi < 2; ++mi)
#pragma unroll
        for (int ni = 0; ni < 2; ++ni) {
            f32x4 acc = (mi == 0) ? (ni == 0 ? acc00 : acc01) : (ni == 0 ? acc10 : acc11);
#pragma unroll
            for (int r = 0; r < 4; ++r) {
                int a = mb * 128 + w * 32 + mi * 16 + r0 + r;
                int o = nb * 32 + ni * 16 + cA;
                int b = a & 127, t = a >> 7;
                out[(size_t)b * (T_ * O_) + (size_t)t * O_ + o] = acc[r] + blin[o];
            }
        }
}

// ---------------- launch ----------------

extern "C" void kernel_launch(void* const* d_in, const int* in_sizes, int n_in,
                              void* d_out, int out_size, void* d_ws, size_t ws_size,
                              hipStream_t stream) {
    const float* x     = (const float*)d_in[0];
    const float* W_ih0 = (const float*)d_in[1];
    const float* W_hh0 = (const float*)d_in[2];
    const float* b_ih0 = (const float*)d_in[3];
    const float* b_hh0 = (const float*)d_in[4];
    const float* W_ih1 = (const float*)d_in[5];
    const float* W_hh1 = (const float*)d_in[6];
    const float* b_ih1 = (const float*)d_in[7];
    const float* b_hh1 = (const float*)d_in[8];
    const float* W_lin = (const float*)d_in[9];
    const float* b_lin = (const float*)d_in[10];
    float* out = (float*)d_out;

    char* ws = (char*)d_ws;
    __bf16* Whh0img = (__bf16*)ws; ws += (size_t)4096 * 1024 * 2;      // 8.4 MB
    __bf16* Wih0s   = (__bf16*)ws; ws += (size_t)4096 * 512 * 2;       // 4.2 MB
    __bf16* Whh1img = (__bf16*)ws; ws += (size_t)4096 * 1024 * 2;      // 8.4 MB
    __bf16* Wih1s   = (__bf16*)ws; ws += (size_t)4096 * 1024 * 2;      // 8.4 MB
    __bf16* Wlb     = (__bf16*)ws; ws += (size_t)512 * 1024 * 2;       // 1 MB
    float* bias0p   = (float*)ws;  ws += (size_t)4096 * 4;
    float* bias1p   = (float*)ws;  ws += (size_t)4096 * 4;
    __bf16* xb      = (__bf16*)ws; ws += (size_t)T_ * B_ * I_ * 2;     // 67 MB
    __bf16* h1all   = (__bf16*)ws; ws += (size_t)(T_ + 1) * B_ * H_ * 2; // 134.5 MB
    __bf16* h2all   = (__bf16*)ws; ws += (size_t)(T_ + 1) * B_ * H_ * 2; // 134.5 MB
    float* xg1buf   = (float*)ws;  ws += (size_t)4 * B_ * 4096 * 4;    // 8.4 MB
    int* bar_cnt    = (int*)ws;    ws += 4096;                          // 32 groups, 128B apart
    int* bar_root   = (int*)ws;    ws += 4096;

    // prep
    pack_img_kernel<<<dim3(128, 32), 256, 0, stream>>>(W_hh0, Whh0img, 32, H_);
    pack_img_kernel<<<dim3(128, 16), 256, 0, stream>>>(W_ih0, Wih0s, 16, I_);
    pack_img_kernel<<<dim3(128, 32), 256, 0, stream>>>(W_hh1, Whh1img, 32, H_);
    pack_img_kernel<<<dim3(128, 32), 256, 0, stream>>>(W_ih1, Wih1s, 32, H_);
    pack_bias_kernel<<<16, 256, 0, stream>>>(b_ih0, b_hh0, bias0p);
    pack_bias_kernel<<<16, 256, 0, stream>>>(b_ih1, b_hh1, bias1p);
    pack_lin_kernel<<<(512 * 1024) / 256, 256, 0, stream>>>(W_lin, Wlb);
    xpose_kernel<<<B_ * T_, 256, 0, stream>>>(x, xb);
    hipMemsetAsync(h1all, 0, (size_t)B_ * H_ * 2, stream);   // slot 0 = h1[-1] = 0
    hipMemsetAsync(h2all, 0, (size_t)B_ * H_ * 2, stream);   // slot 0 = h2[-1] = 0
    hipMemsetAsync(bar_cnt, 0, 8192, stream);                 // counters + root

    // persistent recurrence (cooperative: guarantees co-residency for barrier)
    {
        // allow 128 KB dynamic LDS (gfx950 has 160 KB/CU; 1 block/CU here)
        hipFuncSetAttribute((const void*)lstm_persist,
                            hipFuncAttributeMaxDynamicSharedMemorySize, 131072);
        void* kargs[] = {
            (void*)&Whh0img, (void*)&Wih0s, (void*)&Whh1img, (void*)&Wih1s,
            (void*)&bias0p, (void*)&bias1p, (void*)&xb,
            (void*)&h1all, (void*)&h2all, (void*)&xg1buf,
            (void*)&bar_cnt, (void*)&bar_root
        };
        hipLaunchCooperativeKernel((const void*)lstm_persist, dim3(256), dim3(512),
                                   kargs, 131072, stream);
    }

    // final linear: reads h2 slots 1..512
    final_kernel<<<512 * 16, 256, 0, stream>>>(h2all + (size_t)B_ * H_, Wlb, b_lin, out);
}